// Round 3
// baseline (813.853 us; speedup 1.0000x reference)
//
#include <hip/hip_runtime.h>
#include <cmath>

#define BB 8
#define NN 2048
#define CC 512
#define HH 8
#define DD 64
#define FF 1536
#define MM (BB*NN)   // 16384

typedef _Float16 half_t;
typedef __attribute__((ext_vector_type(8))) _Float16 half8;
typedef __attribute__((ext_vector_type(4))) _Float16 half4;
typedef __attribute__((ext_vector_type(4))) float floatx4;
typedef __attribute__((ext_vector_type(16))) float floatx16;
typedef __attribute__((ext_vector_type(4))) float fx4;

#define LOG2E 1.44269504088896f

// async global->LDS, 16 B per lane; LDS dest must be wave-uniform base (+lane*16)
typedef const __attribute__((address_space(1))) unsigned int* gas_ptr;
typedef __attribute__((address_space(3))) unsigned int* las_ptr;
__device__ __forceinline__ void gld16(const half_t* g, half_t* l) {
  __builtin_amdgcn_global_load_lds((gas_ptr)g, (las_ptr)l, 16, 0, 0);
}

// ---------------------------------------------------------------------------
// fp32 -> fp16 convert (8 elems/thread)
// ---------------------------------------------------------------------------
__global__ __launch_bounds__(256) void cvt_kernel(
    const float* __restrict__ s, half_t* __restrict__ d, int n8) {
  int i = blockIdx.x * 256 + threadIdx.x;
  if (i < n8) {
    float4 a = ((const float4*)s)[i * 2], b = ((const float4*)s)[i * 2 + 1];
    half8 h;
    h[0] = (half_t)a.x; h[1] = (half_t)a.y; h[2] = (half_t)a.z; h[3] = (half_t)a.w;
    h[4] = (half_t)b.x; h[5] = (half_t)b.y; h[6] = (half_t)b.z; h[7] = (half_t)b.w;
    ((half8*)d)[i] = h;
  }
}

// ---------------------------------------------------------------------------
// RoPE cos/sin table: tab[p][j] = (cos, sin)(p * 10000^(-2j/64)), p<2048, j<32
// ---------------------------------------------------------------------------
__global__ __launch_bounds__(256) void rope_tab_kernel(float2* __restrict__ tab) {
  int i = blockIdx.x * 256 + threadIdx.x;       // 65536 entries
  int p = i >> 5, j = i & 31;
  float ang = (float)p * __powf(10000.0f, -(float)(2 * j) * (1.0f / 64.0f));
  float sv, cv;
  __sincosf(ang, &sv, &cv);
  tab[i] = make_float2(cv, sv);
}

// ---------------------------------------------------------------------------
// Kernel 1: qkv = x @ W_qkv^T  (fp16 MFMA, 128x128 tile, BK=32, 4 waves)
// Fused epilogue: RoPE via precomputed table (+ q scale incl. log2e)
// -> Qh/Kh fp16 (B,H,N,D); V -> LDS transpose -> Vt fp16 (B,H,D,N).
// ---------------------------------------------------------------------------
__global__ __launch_bounds__(256) void qkv_mfma_kernel(
    const half_t* __restrict__ Ah,   // (16384, 512)
    const half_t* __restrict__ Bh,   // (1536, 512)
    const int*   __restrict__ ncp,
    const float2* __restrict__ tab,  // (2048, 32) cos/sin
    half_t* __restrict__ Qh, half_t* __restrict__ Kh, half_t* __restrict__ Vt)
{
  __shared__ union {
    struct { half_t A[128 * 32]; half_t B[128 * 32]; } s;   // 16 KB
    half_t T[4][64 * 68];                                   // 34.8 KB (V epilogue)
  } sm;

  const int tid  = threadIdx.x;
  const int wave = tid >> 6, lane = tid & 63;
  const int L15  = lane & 15, quad = lane >> 4;
  const int wm = (wave & 1) * 64, wn = (wave >> 1) * 64;
  const int m0 = blockIdx.x * 128;
  const int f0 = blockIdx.y * 128;

  const int srow = lane >> 2;            // 0..15
  const int scolh = (lane & 3) * 8;      // half offset within row
  const half_t* Ag = Ah + (size_t)(m0 + wave * 16 + srow) * CC + scolh;
  const half_t* Bg = Bh + (size_t)(f0 + wave * 16 + srow) * CC + scolh;
  half_t* Al = &sm.s.A[(wave * 16) * 32];
  half_t* Bl = &sm.s.B[(wave * 16) * 32];

  floatx4 acc[4][4];
#pragma unroll
  for (int i = 0; i < 4; ++i)
#pragma unroll
    for (int j = 0; j < 4; ++j) acc[i][j] = (floatx4){0.f, 0.f, 0.f, 0.f};

  for (int k0 = 0; k0 < CC; k0 += 32) {
    __syncthreads();
    gld16(Ag + k0,            Al);
    gld16(Ag + k0 + 64 * CC,  Al + 64 * 32);
    gld16(Bg + k0,            Bl);
    gld16(Bg + k0 + 64 * CC,  Bl + 64 * 32);
    __syncthreads();
    half8 af[4], bf[4];
#pragma unroll
    for (int mi = 0; mi < 4; ++mi)
      af[mi] = *(const half8*)&sm.s.A[(wm + mi * 16 + L15) * 32 + quad * 8];
#pragma unroll
    for (int ni = 0; ni < 4; ++ni)
      bf[ni] = *(const half8*)&sm.s.B[(wn + ni * 16 + L15) * 32 + quad * 8];
#pragma unroll
    for (int mi = 0; mi < 4; ++mi)
#pragma unroll
      for (int ni = 0; ni < 4; ++ni)
        acc[mi][ni] = __builtin_amdgcn_mfma_f32_16x16x32_f16(af[mi], bf[ni], acc[mi][ni], 0, 0, 0);
  }

  const int which = f0 >> 9;         // block-uniform (128 | 512)
  const int b     = m0 >> 11;        // block-uniform
  const int n_base = (m0 & 2047) + wm;

  if (which < 2) {
    const int nc = *ncp;
    half_t* dst = which ? Kh : Qh;
    const float qscale = which ? 1.0f : (0.125f * LOG2E);
#pragma unroll
    for (int ni = 0; ni < 4; ++ni) {
      const int f = f0 + wn + ni * 16 + L15;
      const int h = (f >> 6) & 7;
      const int d = f & 63;
      const float sgn = (d & 1) ? 1.0f : -1.0f;
      const float2* tj = tab + (d >> 1);
#pragma unroll
      for (int mi = 0; mi < 4; ++mi)
#pragma unroll
        for (int r = 0; r < 4; ++r) {
          const int n = n_base + mi * 16 + quad * 4 + r;
          float v = acc[mi][ni][r];
          float p = __shfl_xor(v, 1, 64);   // RoPE partner (d ^ 1)
          if (n >= nc) {
            float2 cs = tj[(size_t)(n - nc) * 32];
            v = v * cs.x + sgn * p * cs.y;
          }
          dst[(((size_t)(b * HH + h) * NN + n) << 6) + d] = (half_t)(v * qscale);
        }
    }
  } else {
    // V: per-wave 64x64 transpose through LDS -> (B,H,D,N)
    __syncthreads();   // all waves done reading sm.s (union overwrite)
#pragma unroll
    for (int ni = 0; ni < 4; ++ni)
#pragma unroll
      for (int mi = 0; mi < 4; ++mi)
#pragma unroll
        for (int r = 0; r < 4; ++r)
          sm.T[wave][(ni * 16 + L15) * 68 + mi * 16 + quad * 4 + r] = (half_t)acc[mi][ni][r];
    __syncthreads();
    const int h = ((f0 + wn) >> 6) & 7;
    const size_t gbase = ((size_t)(b * HH + h) * DD + lane) * NN + n_base;
#pragma unroll
    for (int c = 0; c < 8; ++c)
      *(half8*)(Vt + gbase + c * 8) = *(const half8*)&sm.T[wave][lane * 68 + c * 8];
  }
}

// ---------------------------------------------------------------------------
// Kernel 2: flash attention, swapped-operand 32x32x16 MFMA.
// This round: 8-wave (512-thread) blocks, two k-groups per block.
//   group g (waves 4g..4g+3) computes k-tiles 2s+g (16 tiles each) over the
//   same 128 q-rows; each group single-buffers its own 16 KB K/V half.
//   Grid 1024 -> 4 blocks/CU -> 32 waves/CU (100% occupancy, VGPR<=64).
//   End: group 1 dumps (acc,l) to LDS (reusing KV), group 0 merges + stores.
// ---------------------------------------------------------------------------
#define EXP2_OFF 4.3280851f   // 3 * log2(e)
__global__ __launch_bounds__(512, 8) void flash_mfma_kernel(
    const half_t* __restrict__ Qh,   // (B,H,N,D)  (q pre-scaled by 0.125*log2e)
    const half_t* __restrict__ Kh,   // (B,H,N,D)
    const half_t* __restrict__ Vt,   // (B,H,D,N)
    const float*  __restrict__ mask, // (B,N)
    half_t* __restrict__ O)          // (B,N,C) fp16
{
  __shared__ half_t KV[2][2][64 * 64];   // [grp][K|V][row*64 + e]  32 KB
  __shared__ float  Ll[128];             // group-1 l values

  const int tid  = threadIdx.x;
  const int wave = tid >> 6;            // 0..7
  const int wg   = wave & 3;            // wave within group
  const int grp  = wave >> 2;           // k-group 0/1
  const int lane = tid & 63;
  const int l31  = lane & 31;
  const int hi   = lane >> 5;           // 0/1
  const int l7   = lane & 7;

  // XCD-aware decode: blocks with the same head share blockIdx%8 (same XCD)
  const int bid  = blockIdx.x;          // 0..1023
  const int xcd  = bid & 7;
  const int slot = bid >> 3;            // 0..127
  const int qt   = slot & 15;           // 16 q-tiles of 128 rows
  const int head = (slot >> 4) * 8 + xcd;   // 0..63
  const int b    = head >> 3;
  const int h    = head & 7;

  const half_t* Kt_base = Kh + ((((size_t)b * HH + h) * NN) << 6);
  const half_t* Vt_base = Vt + (((size_t)b * HH + h) * DD) * NN;

  // Q B-fragments: q = qt*128 + wg*32 + l31 ; k-dim elem = kd*16 + hi*8 + j
  half8 qf[4];
  {
    const half_t* Qp =
        Qh + ((((size_t)b * HH + h) * NN + qt * 128 + wg * 32 + l31) << 6) + hi * 8;
#pragma unroll
    for (int kd = 0; kd < 4; ++kd) qf[kd] = *(const half8*)(Qp + kd * 16);
  }

  // staging source pointers, pre-swizzled: LDS linear slot sl of row holds
  // source 16B-group (sl ^ (row&7)); row&7 == lane>>3 here.
  const int r8  = lane >> 3;                 // 0..7
  const int dof = ((l7 ^ r8) << 3);          // halfs
  const half_t* kbase = Kt_base + (((size_t)(grp * 64 + wg * 16 + r8)) << 6) + dof;
  const half_t* vbase = Vt_base + (size_t)(wg * 16 + r8) * NN + grp * 64 + dof;

  // LDS read addrs (bytes); group base baked in; t offset added as immediate.
  int adK[4], adV[4];
#pragma unroll
  for (int c = 0; c < 4; ++c) {
    adK[c] = grp * 16384 + l31 * 128 + ((((c << 1) | hi) ^ l7) << 4);
    adV[c] = grp * 16384 + 8192 + l31 * 128 + ((((c << 1) | hi) ^ l7) << 4);
  }
  const char* L = (const char*)KV;

  floatx16 acc[2];
#pragma unroll
  for (int dt = 0; dt < 2; ++dt)
#pragma unroll
    for (int r = 0; r < 16; ++r) acc[dt][r] = 0.f;
  float l_part = 0.f;

  const float* mkb = mask + (size_t)b * NN + grp * 64 + hi * 4;

#define STAGE_KV()                                                            \
  {                                                                           \
    gld16(kbase,          &KV[grp][0][wg * 1024]);                            \
    gld16(kbase + 512,    &KV[grp][0][wg * 1024 + 512]);                      \
    gld16(vbase,          &KV[grp][1][wg * 1024]);                            \
    gld16(vbase + 8 * NN, &KV[grp][1][wg * 1024 + 512]);                      \
    kbase += 8192; vbase += 128;                                              \
  }

#define COMPUTE()                                                             \
  _Pragma("unroll")                                                           \
  for (int t = 0; t < 2; ++t) {                                               \
    fx4 m4[4];                                                                \
    _Pragma("unroll")                                                         \
    for (int r2 = 0; r2 < 4; ++r2)                                            \
      m4[r2] = *(const fx4*)(mkb + t * 32 + r2 * 8);                          \
    floatx16 S;                                                               \
    _Pragma("unroll") for (int r = 0; r < 16; ++r) S[r] = 0.f;                \
    __builtin_amdgcn_s_setprio(1);                                            \
    _Pragma("unroll")                                                         \
    for (int kd = 0; kd < 4; ++kd) {                                          \
      half8 kf = *(const half8*)(L + (adK[kd] + t * 4096));                   \
      S = __builtin_amdgcn_mfma_f32_32x32x16_f16(kf, qf[kd], S, 0, 0, 0);     \
    }                                                                         \
    __builtin_amdgcn_s_setprio(0);                                            \
    _Pragma("unroll")                                                         \
    for (int r = 0; r < 16; ++r) {                                            \
      float p = __builtin_amdgcn_exp2f(fmaf(m4[r >> 2][r & 3], LOG2E, S[r] - EXP2_OFF)); \
      l_part += p;                                                            \
      S[r] = p;                                                               \
    }                                                                         \
    unsigned W[4][2];                                                         \
    _Pragma("unroll")                                                         \
    for (int r2 = 0; r2 < 4; ++r2)                                            \
      _Pragma("unroll")                                                       \
      for (int u = 0; u < 2; ++u) {                                           \
        union { half_t hh[2]; unsigned w; } pk;                               \
        pk.hh[0] = (half_t)S[r2 * 4 + 2 * u];                                 \
        pk.hh[1] = (half_t)S[r2 * 4 + 2 * u + 1];                             \
        W[r2][u] = pk.w;                                                      \
      }                                                                       \
    _Pragma("unroll")                                                         \
    for (int ksl = 0; ksl < 2; ++ksl) {                                       \
      unsigned A0 = W[2 * ksl][0],     A1 = W[2 * ksl][1];                    \
      unsigned B0 = W[2 * ksl + 1][0], B1 = W[2 * ksl + 1][1];                \
      unsigned pA0 = __shfl_xor(A0, 32, 64), pA1 = __shfl_xor(A1, 32, 64);    \
      unsigned pB0 = __shfl_xor(B0, 32, 64), pB1 = __shfl_xor(B1, 32, 64);    \
      union { unsigned u4[4]; half8 v; } pw;                                  \
      pw.u4[0] = hi ? pB0 : A0;                                               \
      pw.u4[1] = hi ? pB1 : A1;                                               \
      pw.u4[2] = hi ? B0 : pA0;                                               \
      pw.u4[3] = hi ? B1 : pA1;                                               \
      const int ks = t * 2 + ksl;                                             \
      __builtin_amdgcn_s_setprio(1);                                          \
      _Pragma("unroll")                                                       \
      for (int dt = 0; dt < 2; ++dt) {                                        \
        half8 vf = *(const half8*)(L + (adV[ks] + dt * 4096));                \
        acc[dt] = __builtin_amdgcn_mfma_f32_32x32x16_f16(pw.v, vf, acc[dt], 0, 0, 0); \
      }                                                                       \
      __builtin_amdgcn_s_setprio(0);                                          \
    }                                                                         \
  }

  // prologue: each group stages its first tile (tile grp)
  STAGE_KV()
  asm volatile("s_waitcnt vmcnt(0)");
  __builtin_amdgcn_s_barrier();
  __builtin_amdgcn_sched_barrier(0);

#pragma unroll 1
  for (int s = 0; s < 15; ++s) {       // group g computes tiles 2s+g
    COMPUTE()
    __builtin_amdgcn_sched_barrier(0);
    __builtin_amdgcn_s_barrier();      // all waves done reading KV
    STAGE_KV()                         // tile 2(s+1)+g -> own buffer
    asm volatile("s_waitcnt vmcnt(0)");
    __builtin_amdgcn_s_barrier();      // all stages visible
    __builtin_amdgcn_sched_barrier(0);
    mkb += 128;
  }
  COMPUTE()                            // tiles 30 (grp 0) / 31 (grp 1)

#undef STAGE_KV
#undef COMPUTE

  // ---- cross-group merge (fixed-offset softmax is additive) ----
  __builtin_amdgcn_s_barrier();        // KV reads done before overwrite
  l_part += __shfl_xor(l_part, 32, 64);   // sum the two lane-halves

  float* Lf = (float*)KV;              // 8192 floats == 32 KB
  if (grp) {
#pragma unroll
    for (int dt = 0; dt < 2; ++dt)
#pragma unroll
      for (int r = 0; r < 16; ++r) {
        const int ql = (r & 3) + 8 * (r >> 2) + 4 * hi;
        Lf[wg * 2048 + ql * 64 + dt * 32 + l31] = acc[dt][r];
      }
    if (!hi) Ll[wg * 32 + l31] = l_part;
  }
  __builtin_amdgcn_s_barrier();
  if (!grp) {
    const float lt = l_part + Ll[wg * 32 + l31];
    const size_t orow = (size_t)b * NN + qt * 128 + wg * 32;
#pragma unroll
    for (int r = 0; r < 16; ++r) {
      const int ql  = (r & 3) + 8 * (r >> 2) + 4 * hi;   // 0..31
      const float iv = 1.0f / __shfl(lt, ql, 64);
      const float a0 = acc[0][r] + Lf[wg * 2048 + ql * 64 + l31];
      const float a1 = acc[1][r] + Lf[wg * 2048 + ql * 64 + 32 + l31];
      const size_t ro = ((orow + ql) << 9) + (h << 6) + l31;
      O[ro]      = (half_t)(a0 * iv);
      O[ro + 32] = (half_t)(a1 * iv);
    }
  }
}

// ---------------------------------------------------------------------------
// Kernel 3: out = O @ W_proj^T + b_proj  (fp16 MFMA, fp32 out)  [unchanged]
// ---------------------------------------------------------------------------
__global__ __launch_bounds__(256) void proj_mfma_kernel(
    const half_t* __restrict__ Ah,   // (16384, 512) fp16
    const half_t* __restrict__ Bh,   // (512, 512) fp16
    const float* __restrict__ bias,  // (512,)
    float* __restrict__ out)         // (16384, 512)
{
  __shared__ half_t As[128 * 32];
  __shared__ half_t Bs[128 * 32];

  const int tid  = threadIdx.x;
  const int wave = tid >> 6, lane = tid & 63;
  const int L15  = lane & 15, quad = lane >> 4;
  const int wm = (wave & 1) * 64, wn = (wave >> 1) * 64;
  const int m0 = blockIdx.x * 128;
  const int f0 = blockIdx.y * 128;

  const int srow = lane >> 2;
  const int scolh = (lane & 3) * 8;
  const half_t* Ag = Ah + (size_t)(m0 + wave * 16 + srow) * CC + scolh;
  const half_t* Bg = Bh + (size_t)(f0 + wave * 16 + srow) * CC + scolh;
  half_t* Al = &As[(wave * 16) * 32];
  half_t* Bl = &Bs[(wave * 16) * 32];

  floatx4 acc[4][4];
#pragma unroll
  for (int i = 0; i < 4; ++i)
#pragma unroll
    for (int j = 0; j < 4; ++j) acc[i][j] = (floatx4){0.f, 0.f, 0.f, 0.f};

  for (int k0 = 0; k0 < CC; k0 += 32) {
    __syncthreads();
    gld16(Ag + k0,           Al);
    gld16(Ag + k0 + 64 * CC, Al + 64 * 32);
    gld16(Bg + k0,           Bl);
    gld16(Bg + k0 + 64 * CC, Bl + 64 * 32);
    __syncthreads();
    half8 af[4], bf[4];
#pragma unroll
    for (int mi = 0; mi < 4; ++mi)
      af[mi] = *(const half8*)&As[(wm + mi * 16 + L15) * 32 + quad * 8];
#pragma unroll
    for (int ni = 0; ni < 4; ++ni)
      bf[ni] = *(const half8*)&Bs[(wn + ni * 16 + L15) * 32 + quad * 8];
#pragma unroll
    for (int mi = 0; mi < 4; ++mi)
#pragma unroll
      for (int ni = 0; ni < 4; ++ni)
        acc[mi][ni] = __builtin_amdgcn_mfma_f32_16x16x32_f16(af[mi], bf[ni], acc[mi][ni], 0, 0, 0);
  }

#pragma unroll
  for (int ni = 0; ni < 4; ++ni) {
    const int f = f0 + wn + ni * 16 + L15;
    const float bv = bias[f];
#pragma unroll
    for (int mi = 0; mi < 4; ++mi)
#pragma unroll
      for (int r = 0; r < 4; ++r)
        out[(size_t)(m0 + wm + mi * 16 + quad * 4 + r) * CC + f] = acc[mi][ni][r] + bv;
  }
}

// ---------------------------------------------------------------------------
extern "C" void kernel_launch(void* const* d_in, const int* in_sizes, int n_in,
                              void* d_out, int out_size, void* d_ws, size_t ws_size,
                              hipStream_t stream) {
  const float* x     = (const float*)d_in[0];
  const float* mask  = (const float*)d_in[1];
  const float* Wqkv  = (const float*)d_in[2];
  const float* Wproj = (const float*)d_in[3];
  const float* bproj = (const float*)d_in[4];
  const int*   ncp   = (const int*)d_in[5];
  float* out = (float*)d_out;

  const size_t per = (size_t)BB * HH * NN * DD;   // 8,388,608
  half_t* xh  = (half_t*)d_ws;
  half_t* Wqh = xh + (size_t)MM * CC;
  half_t* Wph = Wqh + (size_t)FF * CC;
  half_t* Qh  = Wph + (size_t)CC * CC;
  half_t* Kh  = Qh + per;
  half_t* Vt  = Kh + per;
  half_t* Oh  = Vt + per;
  float2* tab = (float2*)(Oh + per);              // 2048*32*8B = 512 KB

  rope_tab_kernel<<<dim3(NN * 32 / 256), 256, 0, stream>>>(tab);
  cvt_kernel<<<dim3(MM * CC / 8 / 256), 256, 0, stream>>>(x, xh, MM * CC / 8);
  cvt_kernel<<<dim3(FF * CC / 8 / 256), 256, 0, stream>>>(Wqkv, Wqh, FF * CC / 8);
  cvt_kernel<<<dim3(CC * CC / 8 / 256), 256, 0, stream>>>(Wproj, Wph, CC * CC / 8);

  qkv_mfma_kernel<<<dim3(MM / 128, FF / 128), 256, 0, stream>>>(xh, Wqh, ncp, tab, Qh, Kh, Vt);
  flash_mfma_kernel<<<dim3(BB * HH * (NN / 128)), 512, 0, stream>>>(Qh, Kh, Vt, mask, Oh);
  proj_mfma_kernel<<<dim3(MM / 128, CC / 128), 256, 0, stream>>>(Oh, Wph, bproj, out);
}